// Round 21
// baseline (220.006 us; speedup 1.0000x reference)
//
#include <hip/hip_runtime.h>

// Geometry: G=256 graphs x 64 nodes, H=8 heads x D=8, IN_DIM=EDGE_DIM=64
// EF = 1048576 full edges, ES = 262144 sparse edges.
// edge f = b*4096 + i*64 + j (src=i, dst=j); sparse s = b*1024 + j*16 + k, i=(j+1+k)&63.
//
// Staging (floats, d_out's eout region, dead before eoutT writes):
//   Qs @0, Ks @1048576, Vs @2097152, PEs @3145728.
//   d_ws: scsp [262144*8] @0, M2 [576] @2097152, Tm [73*64] @2098176.
// NOTE meta-results r15-r20: (1) walls = ISSUE PATTERN: bulk coalesced loads
// stream at 2-2.9TB/s even at low occupancy; interleaved load-compute idles
// at ~750GB/s. (2) LDS-unit issue bounds kernels with >1 b128/~8 FMAs.
// (3) co-compiled branches share regalloc; check VGPR per round.
// (4) r18-r20 spills: the scheduler hoists DS_READ results across any
// unpinned unrolled region (32 iters x 16 floats = 512 regs!) -> spill.
// sched_barrier(0) must bound EVERY region incl. compute tails, sized so
// (base ~62 regs) + (iters x 16 LDS dests) < cap. 2-iter regions -> ~94.

// qkv (blocks 0..255) + pe (blocks 256..767), independent. (r14-proven ~19us)
__global__ __launch_bounds__(512, 2) void qkvpe_kernel(
    const float* __restrict__ h,
    const float* __restrict__ e,
    const float* __restrict__ Wq, const float* __restrict__ bq,
    const float* __restrict__ Wk, const float* __restrict__ bk,
    const float* __restrict__ Wv, const float* __restrict__ bv,
    const float* __restrict__ Wpe, const float* __restrict__ bpe,
    float* __restrict__ Qs, float* __restrict__ Ks, float* __restrict__ Vs,
    float* __restrict__ PEs)
{
    const int t = threadIdx.x;
    if (blockIdx.x < 256) {
        const int b    = blockIdx.x;
        const int lane = t & 63;
        const int wu   = __builtin_amdgcn_readfirstlane(t >> 6);   // 8 cols per wave
        const float* hrow = h + (size_t)(b * 64 + lane) * 64;
        float accQ[8], accK[8], accV[8];
        #pragma unroll
        for (int cc = 0; cc < 8; ++cc) {
            const int c = wu * 8 + cc;
            accQ[cc] = bq[c]; accK[cc] = bk[c]; accV[cc] = bv[c];
        }
        #pragma unroll 1
        for (int k0 = 0; k0 < 4; ++k0) {
            float hv[16];
            #pragma unroll
            for (int u = 0; u < 4; ++u) {
                const float4 x = ((const float4*)hrow)[k0 * 4 + u];
                hv[u*4+0] = x.x; hv[u*4+1] = x.y; hv[u*4+2] = x.z; hv[u*4+3] = x.w;
            }
            #pragma unroll
            for (int cc = 0; cc < 8; ++cc) {
                const int c = wu * 8 + cc;
                const float* wq  = Wq + c * 64 + k0 * 16;   // wave-uniform -> s_load
                const float* wk  = Wk + c * 64 + k0 * 16;
                const float* wvp = Wv + c * 64 + k0 * 16;
                #pragma unroll
                for (int k = 0; k < 16; ++k) {
                    accQ[cc] = fmaf(hv[k], wq[k],  accQ[cc]);
                    accK[cc] = fmaf(hv[k], wk[k],  accK[cc]);
                    accV[cc] = fmaf(hv[k], wvp[k], accV[cc]);
                }
            }
        }
        const size_t o = (size_t)(b * 64 + lane) * 64 + wu * 8;
        *(float4*)(Qs + o)     = make_float4(accQ[0], accQ[1], accQ[2], accQ[3]);
        *(float4*)(Qs + o + 4) = make_float4(accQ[4], accQ[5], accQ[6], accQ[7]);
        *(float4*)(Ks + o)     = make_float4(accK[0], accK[1], accK[2], accK[3]);
        *(float4*)(Ks + o + 4) = make_float4(accK[4], accK[5], accK[6], accK[7]);
        *(float4*)(Vs + o)     = make_float4(accV[0], accV[1], accV[2], accV[3]);
        *(float4*)(Vs + o + 4) = make_float4(accV[4], accV[5], accV[6], accV[7]);
    } else {
        const int row = (blockIdx.x - 256) * 512 + t;      // 0..ES-1
        const float* erow = e + (size_t)row * 64;
        float acc[8];
        #pragma unroll
        for (int h2 = 0; h2 < 8; ++h2) acc[h2] = bpe[h2];
        #pragma unroll 1
        for (int k0 = 0; k0 < 4; ++k0) {
            float ev[16];
            #pragma unroll
            for (int u = 0; u < 4; ++u) {
                const float4 x = ((const float4*)erow)[k0 * 4 + u];
                ev[u*4+0] = x.x; ev[u*4+1] = x.y; ev[u*4+2] = x.z; ev[u*4+3] = x.w;
            }
            #pragma unroll
            for (int h2 = 0; h2 < 8; ++h2) {
                const float* wp = Wpe + h2 * 64 + k0 * 16;  // uniform -> s_load
                #pragma unroll
                for (int k = 0; k < 16; ++k)
                    acc[h2] = fmaf(ev[k], wp[k], acc[h2]);
            }
        }
        float* p0 = PEs + (size_t)row * 8;
        *(float4*)(p0)     = make_float4(acc[0], acc[1], acc[2], acc[3]);
        *(float4*)(p0 + 4) = make_float4(acc[4], acc[5], acc[6], acc[7]);
    }
}

#define SBAR __builtin_amdgcn_sched_barrier(0)

// ---- attn chunk macros: static indices after unroll (rule #20 safe)
#define LOADR(Rb, c_) { _Pragma("unroll") \
  for (int u_ = 0; u_ < 8; ++u_) \
    Rb[u_] = relBase[(size_t)((c_) * 8 + u_) * 512]; }

// 2 iterations per pinned region: base(~62) + 2x16 LDS dests stays < 128 cap.
#define COMP2(Rb, c_, p_) { _Pragma("unroll") \
  for (int u_ = (p_) * 2; u_ < (p_) * 2 + 2; ++u_) { \
    const int i_ = (c_) * 8 + u_; \
    const float4 kA = *(const float4*)&shK[i_ * 64 + hh * 8]; \
    const float4 kC = *(const float4*)&shK[i_ * 64 + hh * 8 + 4]; \
    float s_ = kA.x * q[0]; \
    s_ = fmaf(kA.y, q[1], s_); s_ = fmaf(kA.z, q[2], s_); s_ = fmaf(kA.w, q[3], s_); \
    s_ = fmaf(kC.x, q[4], s_); s_ = fmaf(kC.y, q[5], s_); s_ = fmaf(kC.z, q[6], s_); \
    s_ = fmaf(kC.w, q[7], s_); \
    s_ = fmaf(s_ * inv_scale, shAdj[i_ * 33 + jl], Rb[u_]); \
    const int kidx_ = (i_ - j - 1) & 63; \
    if (kidx_ < 16) { \
        const int x_ = (jl * 16 + kidx_) * 8 + hh; \
        const float pe_ = shPE[x_]; \
        shPE[x_] = s_; \
        s_ += pe_; \
    } \
    s_ = fminf(fmaxf(s_, -5.f), 5.f); \
    const float ex_ = __expf(s_); \
    den += ex_; \
    const float4 vA = *(const float4*)&shV[i_ * 64 + hh * 8]; \
    const float4 vC = *(const float4*)&shV[i_ * 64 + hh * 8 + 4]; \
    wv[0] = fmaf(ex_, vA.x, wv[0]); wv[1] = fmaf(ex_, vA.y, wv[1]); \
    wv[2] = fmaf(ex_, vA.z, wv[2]); wv[3] = fmaf(ex_, vA.w, wv[3]); \
    wv[4] = fmaf(ex_, vC.x, wv[4]); wv[5] = fmaf(ex_, vC.y, wv[5]); \
    wv[6] = fmaf(ex_, vC.z, wv[6]); wv[7] = fmaf(ex_, vC.w, wv[7]); } }

#define CHUNK8(Rb, c_) \
    COMP2(Rb, c_, 0); SBAR; COMP2(Rb, c_, 1); SBAR; \
    COMP2(Rb, c_, 2); SBAR; COMP2(Rb, c_, 3); SBAR;

// attn: 512 blocks = (b, jhalf), 256 threads = (jl = t>>3, hh = t&7).
// rel via 4-deep rotating 8-reg buffers, refills 4 chunks ahead; EVERY
// 2-iter compute region pinned with sched_barrier(0) (r20 lesson: unpinned
// tails let the scheduler hoist 512 ds_read dests -> 190MB spill).
__global__ __launch_bounds__(256, 2) void attn_kernel(
    const float* __restrict__ Qs, const float* __restrict__ Ks,
    const float* __restrict__ Vs, const float* __restrict__ PEs,
    const float* __restrict__ adj2,
    const float* __restrict__ rel,
    float* __restrict__ wVg,          // [16384*64] = h_out region (normalized wV)
    float* __restrict__ scsp)
{
    __shared__ float shK[64 * 64];    // [i][dim], plain (broadcast rows)
    __shared__ float shV[64 * 64];
    __shared__ float shPE[512 * 8];   // this j-half's proj_e -> sc in place
    __shared__ float shAdj[64 * 33];  // [i][jl]

    const int b2 = blockIdx.x;
    const int b  = b2 >> 1;
    const int j0 = (b2 & 1) << 5;
    const int t  = threadIdx.x;
    const int jl = t >> 3;
    const int hh = t & 7;
    const int j  = j0 + jl;

    // R[i] = rel[b][i][j][hh]; per-i the wave's 64 lanes are consecutive (256B).
    const float* relBase = rel + (size_t)b * 32768 + j0 * 8 + t;
    float RA[8], RB[8], RC[8], RD[8];
    LOADR(RA, 0); LOADR(RB, 1); LOADR(RC, 2); LOADR(RD, 3);   // bulk, pre-barrier

    // ---- stage K, V, PE slice (coalesced), adj (128B segments); q per-thread
    {
        const float4* srcK = (const float4*)(Ks + (size_t)b * 4096);
        const float4* srcV = (const float4*)(Vs + (size_t)b * 4096);
        float4* dK = (float4*)shK; float4* dV = (float4*)shV;
        #pragma unroll
        for (int u = 0; u < 4; ++u) {
            dK[u * 256 + t] = srcK[u * 256 + t];
            dV[u * 256 + t] = srcV[u * 256 + t];
        }
        const float4* srcP = (const float4*)(PEs + ((size_t)b * 1024 + j0 * 16) * 8);
        float4* dP = (float4*)shPE;
        #pragma unroll
        for (int u = 0; u < 4; ++u)
            dP[u * 256 + t] = srcP[u * 256 + t];
    }
    {   // adj: thread (i2 = t>>2, grp = t&3) loads 8 j's of row i2
        const int i2 = t >> 2, grp = t & 3;
        const float* ap = adj2 + (size_t)b * 4096 + i2 * 64 + j0 + grp * 8;
        const float4 a0 = *(const float4*)(ap);
        const float4 a1 = *(const float4*)(ap + 4);
        float* dp = &shAdj[i2 * 33 + grp * 8];
        dp[0] = a0.x; dp[1] = a0.y; dp[2] = a0.z; dp[3] = a0.w;
        dp[4] = a1.x; dp[5] = a1.y; dp[6] = a1.z; dp[7] = a1.w;
    }
    float q[8];
    {
        const float* qp = Qs + (size_t)(b * 64 + j) * 64 + hh * 8;
        const float4 a = *(const float4*)qp;
        const float4 c4 = *(const float4*)(qp + 4);
        q[0]=a.x; q[1]=a.y; q[2]=a.z; q[3]=a.w;
        q[4]=c4.x; q[5]=c4.y; q[6]=c4.z; q[7]=c4.w;
    }
    __syncthreads();

    // ---- i-loop: 8 chunks of 8, computed as 32 pinned 2-iter regions;
    // refills pipelined 4 chunks (~800 cyc) ahead.
    float den = 0.f;
    float wv[8] = {0.f,0.f,0.f,0.f,0.f,0.f,0.f,0.f};
    const float inv_scale = 0.35355339059327379f;  // 1/sqrt(8)
    CHUNK8(RA, 0); LOADR(RA, 4); SBAR;
    CHUNK8(RB, 1); LOADR(RB, 5); SBAR;
    CHUNK8(RC, 2); LOADR(RC, 6); SBAR;
    CHUNK8(RD, 3); LOADR(RD, 7); SBAR;
    CHUNK8(RA, 4);
    CHUNK8(RB, 5);
    CHUNK8(RC, 6);
    CHUNK8(RD, 7);
    __syncthreads();                 // all PE->SC swaps complete

    // ---- coalesced sc dump + normalized wV out
    {
        const float4* src = (const float4*)shPE;
        float4* dst = (float4*)(scsp + ((size_t)b * 1024 + j0 * 16) * 8);
        #pragma unroll
        for (int u = 0; u < 4; ++u)
            dst[u * 256 + t] = src[u * 256 + t];
    }
    const float id = 1.f / den;
    float* wp = wVg + (size_t)(b * 64 + j) * 64 + hh * 8;
    *(float4*)(wp)     = make_float4(wv[0]*id, wv[1]*id, wv[2]*id, wv[3]*id);
    *(float4*)(wp + 4) = make_float4(wv[4]*id, wv[5]*id, wv[6]*id, wv[7]*id);
}

// hout: h_out = wVg @ Wo^T + bo, 4x4 micro-tile; wVg lives IN h_out region.
__global__ __launch_bounds__(256, 2) void hout_kernel(
    const float* __restrict__ wVg,
    const float* __restrict__ Wo, const float* __restrict__ bo,
    float* __restrict__ h_out)
{
    __shared__ float shWT[64 * 69];
    __shared__ float shWoT[64 * 65];

    const int t    = threadIdx.x;
    const int base = blockIdx.x * 64;
    {
        const int r0 = t >> 2, qq = t & 3;
        const float* ep = wVg + (size_t)(base + r0) * 64 + qq * 16;
        #pragma unroll
        for (int v = 0; v < 4; ++v) {
            const float4 x = ((const float4*)ep)[v];
            const int c = qq * 16 + v * 4;
            shWT[(c + 0) * 69 + r0] = x.x;
            shWT[(c + 1) * 69 + r0] = x.y;
            shWT[(c + 2) * 69 + r0] = x.z;
            shWT[(c + 3) * 69 + r0] = x.w;
        }
    }
    {
        const int c0 = t >> 2, qq = t & 3;
        const float* wp = Wo + c0 * 64 + qq * 16;
        #pragma unroll
        for (int v = 0; v < 4; ++v) {
            const float4 x = ((const float4*)wp)[v];
            const int k = qq * 16 + v * 4;
            shWoT[(k + 0) * 65 + c0] = x.x;
            shWoT[(k + 1) * 65 + c0] = x.y;
            shWoT[(k + 2) * 65 + c0] = x.z;
            shWoT[(k + 3) * 65 + c0] = x.w;
        }
    }
    __syncthreads();

    const int rq = t >> 4, cq = t & 15;
    float acc[16];
    {
        const float4 bv = *(const float4*)(bo + cq * 4);
        #pragma unroll
        for (int ri = 0; ri < 4; ++ri) {
            acc[ri*4+0] = bv.x; acc[ri*4+1] = bv.y;
            acc[ri*4+2] = bv.z; acc[ri*4+3] = bv.w;
        }
    }
    #pragma unroll
    for (int k = 0; k < 64; ++k) {
        const float4 ev = *(const float4*)&shWT[k * 69 + rq * 4];
        const float4 wk = *(const float4*)&shWoT[k * 65 + cq * 4];
        acc[0]  = fmaf(ev.x, wk.x, acc[0]);  acc[1]  = fmaf(ev.x, wk.y, acc[1]);
        acc[2]  = fmaf(ev.x, wk.z, acc[2]);  acc[3]  = fmaf(ev.x, wk.w, acc[3]);
        acc[4]  = fmaf(ev.y, wk.x, acc[4]);  acc[5]  = fmaf(ev.y, wk.y, acc[5]);
        acc[6]  = fmaf(ev.y, wk.z, acc[6]);  acc[7]  = fmaf(ev.y, wk.w, acc[7]);
        acc[8]  = fmaf(ev.z, wk.x, acc[8]);  acc[9]  = fmaf(ev.z, wk.y, acc[9]);
        acc[10] = fmaf(ev.z, wk.z, acc[10]); acc[11] = fmaf(ev.z, wk.w, acc[11]);
        acc[12] = fmaf(ev.w, wk.x, acc[12]); acc[13] = fmaf(ev.w, wk.y, acc[13]);
        acc[14] = fmaf(ev.w, wk.z, acc[14]); acc[15] = fmaf(ev.w, wk.w, acc[15]);
    }
    #pragma unroll
    for (int ri = 0; ri < 4; ++ri) {
        float* orow = h_out + (size_t)(base + rq * 4 + ri) * 64 + cq * 4;
        *(float4*)orow = make_float4(acc[ri*4+0], acc[ri*4+1], acc[ri*4+2], acc[ri*4+3]);
    }
}

// prep: M2/bc (fallback) + T[73][64] = [Woe^T ; M2^T ; bc].
__global__ void prep_kernel(const float* __restrict__ Wap, const float* __restrict__ bap,
                            const float* __restrict__ Woe, const float* __restrict__ boe,
                            float* __restrict__ M2, float* __restrict__ Tm, int hasT)
{
    const int tg = blockIdx.x * 64 + threadIdx.x;
    if (tg < 512) {
        const int c = tg >> 3, hq = tg & 7;
        float s = 0.f;
        #pragma unroll 8
        for (int k = 0; k < 64; ++k) s = fmaf(Woe[c * 64 + k], Wap[k * 8 + hq], s);
        M2[tg] = s;
    } else if (tg < 576) {
        const int c = tg - 512;
        float s = boe[c];
        #pragma unroll 8
        for (int k = 0; k < 64; ++k) s = fmaf(bap[k], Woe[c * 64 + k], s);
        M2[512 + c] = s;
    } else if (hasT && tg < 576 + 73 * 64) {
        const int idx = tg - 576;
        const int k = idx >> 6, c = idx & 63;
        float v;
        if (k < 64) {
            v = Woe[c * 64 + k];
        } else if (k < 72) {
            const int hq = k - 64;
            v = 0.f;
            #pragma unroll 8
            for (int kk = 0; kk < 64; ++kk)
                v = fmaf(Woe[c * 64 + kk], Wap[kk * 8 + hq], v);
        } else {
            v = boe[c];
            #pragma unroll 8
            for (int kk = 0; kk < 64; ++kk)
                v = fmaf(bap[kk], Woe[c * 64 + kk], v);
        }
        Tm[k * 64 + c] = v;
    }
}

// eoutT: ZERO-LDS flat k-outer (r17). 256 thr = 64 rows x 4 col-groups.
// ev[72] bulk in regs; weights via wave-uniform s_load per k (scalar pipe).
__global__ __launch_bounds__(256, 2) void eoutT_kernel(
    const float* __restrict__ e,
    const float* __restrict__ scsp,
    const float* __restrict__ Tm,      // [73][64]: Woe^T k=0..63, M2^T k=64..71, bc
    float* __restrict__ e_out)
{
    const int t   = threadIdx.x;
    const int r   = t & 63;
    const int w   = __builtin_amdgcn_readfirstlane(t >> 6);   // col group 0..3
    const int row = blockIdx.x * 64 + r;

    float ev[72];
    {
        const float* ep = e + (size_t)row * 64;
        #pragma unroll
        for (int v = 0; v < 16; ++v) {
            const float4 x = ((const float4*)ep)[v];
            ev[v*4+0] = x.x; ev[v*4+1] = x.y; ev[v*4+2] = x.z; ev[v*4+3] = x.w;
        }
        const float4 s0 = *(const float4*)(scsp + (size_t)row * 8);
        const float4 s1 = *(const float4*)(scsp + (size_t)row * 8 + 4);
        ev[64]=s0.x; ev[65]=s0.y; ev[66]=s0.z; ev[67]=s0.w;
        ev[68]=s1.x; ev[69]=s1.y; ev[70]=s1.z; ev[71]=s1.w;
    }
    const float* wbase = Tm + w * 16;              // wave-uniform
    float acc[16];
    #pragma unroll
    for (int u = 0; u < 16; ++u) acc[u] = wbase[72 * 64 + u];   // bc via s_load
    #pragma unroll
    for (int k = 0; k < 72; ++k) {
        const float* wk = wbase + k * 64;          // wave-uniform -> s_load_dwordx16
        #pragma unroll
        for (int u = 0; u < 16; ++u)
            acc[u] = fmaf(ev[k], wk[u], acc[u]);   // 16 independent FMAs
    }
    float* orow = e_out + (size_t)row * 64 + w * 16;
    #pragma unroll
    for (int u = 0; u < 4; ++u)
        *(float4*)&orow[u * 4] =
            make_float4(acc[u*4+0], acc[u*4+1], acc[u*4+2], acc[u*4+3]);
}

// Fallback eout if d_ws can't hold Tm (r10 shape).
__global__ __launch_bounds__(256, 2) void eout_kernel(
    const float* __restrict__ e,
    const float* __restrict__ scsp,
    const float* __restrict__ Woe,
    const float* __restrict__ M2g,
    float* __restrict__ e_out)
{
    __shared__ float shE[64 * 64];
    __shared__ float shS[64 * 8];
    const int t    = threadIdx.x;
    const int base = blockIdx.x * 64;
    {
        const int r = t >> 2, qq = t & 3;
        const float* ep = e + (size_t)(base + r) * 64 + qq * 16;
        #pragma unroll
        for (int u = 0; u < 4; ++u) {
            const float4 x = ((const float4*)ep)[u];
            const int cc = qq * 4 + u;
            *(float4*)&shE[r * 64 + ((cc ^ (r & 15)) << 2)] = x;
        }
    }
    if (t < 128) {
        const int r = t >> 1, pp = t & 1;
        *(float4*)&shS[r * 8 + pp * 4] =
            *(const float4*)(scsp + (size_t)(base + r) * 8 + pp * 4);
    }
    __syncthreads();
    const int w = __builtin_amdgcn_readfirstlane(t >> 6);
    const int r = t & 63;
    float sc[8];
    {
        const float4 a  = *(const float4*)&shS[r * 8];
        const float4 c4 = *(const float4*)&shS[r * 8 + 4];
        sc[0]=a.x; sc[1]=a.y; sc[2]=a.z; sc[3]=a.w;
        sc[4]=c4.x; sc[5]=c4.y; sc[6]=c4.z; sc[7]=c4.w;
    }
    float acc[16];
    #pragma unroll
    for (int u = 0; u < 16; ++u) {
        const int c = w * 16 + u;
        float s = M2g[512 + c];
        #pragma unroll
        for (int hq = 0; hq < 8; ++hq)
            s = fmaf(sc[hq], M2g[c * 8 + hq], s);
        acc[u] = s;
    }
    #pragma unroll
    for (int k0 = 0; k0 < 4; ++k0) {
        float ev[16];
        #pragma unroll
        for (int v = 0; v < 4; ++v) {
            const int cc = k0 * 4 + v;
            const float4 x = *(const float4*)&shE[r * 64 + ((cc ^ (r & 15)) << 2)];
            ev[v*4+0] = x.x; ev[v*4+1] = x.y; ev[v*4+2] = x.z; ev[v*4+3] = x.w;
        }
        #pragma unroll
        for (int u = 0; u < 16; ++u) {
            const float* wr = Woe + (w * 16 + u) * 64 + k0 * 16;
            #pragma unroll
            for (int k = 0; k < 16; ++k)
                acc[u] = fmaf(ev[k], wr[k], acc[u]);
        }
    }
    float* orow = e_out + (size_t)(base + r) * 64 + w * 16;
    #pragma unroll
    for (int u = 0; u < 4; ++u)
        *(float4*)&orow[u * 4] =
            make_float4(acc[u*4+0], acc[u*4+1], acc[u*4+2], acc[u*4+3]);
}

extern "C" void kernel_launch(void* const* d_in, const int* in_sizes, int n_in,
                              void* d_out, int out_size, void* d_ws, size_t ws_size,
                              hipStream_t stream) {
    const float* h    = (const float*)d_in[0];
    const float* e    = (const float*)d_in[1];
    const float* adj2 = (const float*)d_in[2];
    const float* rel  = (const float*)d_in[3];
    const float* Wq   = (const float*)d_in[4];  const float* bq  = (const float*)d_in[5];
    const float* Wk   = (const float*)d_in[6];  const float* bk  = (const float*)d_in[7];
    const float* Wv   = (const float*)d_in[8];  const float* bv  = (const float*)d_in[9];
    const float* Wpe  = (const float*)d_in[10]; const float* bpe = (const float*)d_in[11];
    const float* Wap  = (const float*)d_in[12]; const float* bap = (const float*)d_in[13];
    const float* Wo   = (const float*)d_in[14]; const float* bo  = (const float*)d_in[15];
    const float* Woe  = (const float*)d_in[16]; const float* boe = (const float*)d_in[17];

    float* out  = (float*)d_out;
    float* hout = out;                        // [16384*64]; holds wVg between kernels
    float* eout = out + 16384 * 64;           // [262144*64], staging (dead at eout time)
    float* Qs   = eout;
    float* Ks   = eout + 1048576;
    float* Vs   = eout + 2097152;
    float* PEs  = eout + 3145728;             // ends 5242880
    float* ws   = (float*)d_ws;
    float* scsp = ws;                         // [262144*8]
    float* M2g  = ws + 2097152;               // [576]
    float* Tm   = ws + 2098176;               // [73*64]
    const int hasT = (ws_size >= (size_t)(2098176 + 73 * 64) * sizeof(float)) ? 1 : 0;

    prep_kernel<<<dim3(82), dim3(64), 0, stream>>>(Wap, bap, Woe, boe, M2g, Tm, hasT);
    qkvpe_kernel<<<dim3(768), dim3(512), 0, stream>>>(
        h, e, Wq, bq, Wk, bk, Wv, bv, Wpe, bpe, Qs, Ks, Vs, PEs);
    attn_kernel<<<dim3(512), dim3(256), 0, stream>>>(
        Qs, Ks, Vs, PEs, adj2, rel, hout /*wVg*/, scsp);
    hout_kernel<<<dim3(256), dim3(256), 0, stream>>>(hout, Wo, bo, hout);
    if (hasT)
        eoutT_kernel<<<dim3(4096), dim3(256), 0, stream>>>(e, scsp, Tm, eout);
    else
        eout_kernel<<<dim3(4096), dim3(256), 0, stream>>>(e, scsp, Woe, M2g, eout);
}

// Round 22
// 141.369 us; speedup vs baseline: 1.5563x; 1.5563x over previous
//
#include <hip/hip_runtime.h>

// Geometry: G=256 graphs x 64 nodes, H=8 heads x D=8, IN_DIM=EDGE_DIM=64
// EF = 1048576 full edges, ES = 262144 sparse edges.
// edge f = b*4096 + i*64 + j (src=i, dst=j); sparse s = b*1024 + j*16 + k, i=(j+1+k)&63.
//
// Staging (floats, d_out's eout region, dead before eoutT writes):
//   Qs @0, Ks @1048576, Vs @2097152, PEs @3145728.
//   d_ws: scsp [262144*8] @0, M2 [576] @2097152, Tm [73*64] @2098176.
// NOTE meta-results r15-r21: (1) walls = ISSUE PATTERN: bulk coalesced loads
// stream at 2-2.9TB/s even at 1 block/CU; in-loop load-compute idles ~750GB/s.
// (2) LDS-unit issue bounds kernels with >1 b128/~8 FMAs. (3) co-compiled
// branches share regalloc. (4) r18-r21: holding 64 streamed floats in VGPRs
// is UNWINNABLE (scheduler+allocator spill 180-200MB regardless of
// sched_barrier granularity). Winning combo: bulk-stage into BIG LDS
// (160KB/CU available; 132KB here) + r13's clean LDS-broadcast compute.

// qkv (blocks 0..255) + pe (blocks 256..767), independent. (r14-proven ~19us)
__global__ __launch_bounds__(512, 2) void qkvpe_kernel(
    const float* __restrict__ h,
    const float* __restrict__ e,
    const float* __restrict__ Wq, const float* __restrict__ bq,
    const float* __restrict__ Wk, const float* __restrict__ bk,
    const float* __restrict__ Wv, const float* __restrict__ bv,
    const float* __restrict__ Wpe, const float* __restrict__ bpe,
    float* __restrict__ Qs, float* __restrict__ Ks, float* __restrict__ Vs,
    float* __restrict__ PEs)
{
    const int t = threadIdx.x;
    if (blockIdx.x < 256) {
        const int b    = blockIdx.x;
        const int lane = t & 63;
        const int wu   = __builtin_amdgcn_readfirstlane(t >> 6);   // 8 cols per wave
        const float* hrow = h + (size_t)(b * 64 + lane) * 64;
        float accQ[8], accK[8], accV[8];
        #pragma unroll
        for (int cc = 0; cc < 8; ++cc) {
            const int c = wu * 8 + cc;
            accQ[cc] = bq[c]; accK[cc] = bk[c]; accV[cc] = bv[c];
        }
        #pragma unroll 1
        for (int k0 = 0; k0 < 4; ++k0) {
            float hv[16];
            #pragma unroll
            for (int u = 0; u < 4; ++u) {
                const float4 x = ((const float4*)hrow)[k0 * 4 + u];
                hv[u*4+0] = x.x; hv[u*4+1] = x.y; hv[u*4+2] = x.z; hv[u*4+3] = x.w;
            }
            #pragma unroll
            for (int cc = 0; cc < 8; ++cc) {
                const int c = wu * 8 + cc;
                const float* wq  = Wq + c * 64 + k0 * 16;   // wave-uniform -> s_load
                const float* wk  = Wk + c * 64 + k0 * 16;
                const float* wvp = Wv + c * 64 + k0 * 16;
                #pragma unroll
                for (int k = 0; k < 16; ++k) {
                    accQ[cc] = fmaf(hv[k], wq[k],  accQ[cc]);
                    accK[cc] = fmaf(hv[k], wk[k],  accK[cc]);
                    accV[cc] = fmaf(hv[k], wvp[k], accV[cc]);
                }
            }
        }
        const size_t o = (size_t)(b * 64 + lane) * 64 + wu * 8;
        *(float4*)(Qs + o)     = make_float4(accQ[0], accQ[1], accQ[2], accQ[3]);
        *(float4*)(Qs + o + 4) = make_float4(accQ[4], accQ[5], accQ[6], accQ[7]);
        *(float4*)(Ks + o)     = make_float4(accK[0], accK[1], accK[2], accK[3]);
        *(float4*)(Ks + o + 4) = make_float4(accK[4], accK[5], accK[6], accK[7]);
        *(float4*)(Vs + o)     = make_float4(accV[0], accV[1], accV[2], accV[3]);
        *(float4*)(Vs + o + 4) = make_float4(accV[4], accV[5], accV[6], accV[7]);
    } else {
        const int row = (blockIdx.x - 256) * 512 + t;      // 0..ES-1
        const float* erow = e + (size_t)row * 64;
        float acc[8];
        #pragma unroll
        for (int h2 = 0; h2 < 8; ++h2) acc[h2] = bpe[h2];
        #pragma unroll 1
        for (int k0 = 0; k0 < 4; ++k0) {
            float ev[16];
            #pragma unroll
            for (int u = 0; u < 4; ++u) {
                const float4 x = ((const float4*)erow)[k0 * 4 + u];
                ev[u*4+0] = x.x; ev[u*4+1] = x.y; ev[u*4+2] = x.z; ev[u*4+3] = x.w;
            }
            #pragma unroll
            for (int h2 = 0; h2 < 8; ++h2) {
                const float* wp = Wpe + h2 * 64 + k0 * 16;  // uniform -> s_load
                #pragma unroll
                for (int k = 0; k < 16; ++k)
                    acc[h2] = fmaf(ev[k], wp[k], acc[h2]);
            }
        }
        float* p0 = PEs + (size_t)row * 8;
        *(float4*)(p0)     = make_float4(acc[0], acc[1], acc[2], acc[3]);
        *(float4*)(p0 + 4) = make_float4(acc[4], acc[5], acc[6], acc[7]);
    }
}

// attn: r13 structure (proven 58us / VGPR 36 / no spill) + rel & adj staged
// into BIG LDS in one bulk coalesced burst. 512 blocks = (b, jhalf),
// 1024 threads = (q4 = t>>8, j_local = (t>>3)&31, hh = t&7), 16 i's/thread,
// wave-uniform i (broadcast shK/shV rows). i-loop is PURE LDS/VALU.
__global__ __launch_bounds__(1024, 1) void attn_kernel(
    const float* __restrict__ Qs, const float* __restrict__ Ks,
    const float* __restrict__ Vs, const float* __restrict__ PEs,
    const float* __restrict__ adj2,
    const float* __restrict__ rel,
    const float* __restrict__ Wo, const float* __restrict__ bo,
    float* __restrict__ h_out,
    float* __restrict__ scsp)
{
    __shared__ float shK[64 * 64];    // swizzled: row r, colgrp g at r*64+((g^(r&7))<<3)
    __shared__ float shV[64 * 64];    // (shK reused as wV[32][64] after the loop)
    __shared__ float shPE[512 * 8];   // proj_e -> overwritten in-place with sc_sp
    __shared__ float shRed[256 * 9];  // cross-wave partials: [jh][wv0..7, den]
    __shared__ float shRel[64 * 264]; // [i][jh], pad 264 (67.6KB)
    __shared__ float shAdj[64 * 36];  // [i][jl], pad 36 (16B-aligned rows)

    const int b2   = blockIdx.x;
    const int b    = b2 >> 1;
    const int joff = (b2 & 1) << 5;          // 0 or 32
    const int t    = threadIdx.x;

    const int j_local = (t >> 3) & 31;       // 0..31
    const int hh      = t & 7;               // 0..7
    const int q4      = t >> 8;              // 0..3 (i-quarter = wave group)
    const int j       = joff + j_local;

    // ---- bulk staging, all coalesced, one barrier ----
    // rel slice [64 i][256 jh]: 4 float4/thread, each wave-load = 1KB run
    {
        const float* rbase = rel + (size_t)b * 32768 + joff * 8;
        #pragma unroll
        for (int u = 0; u < 4; ++u) {
            const int fidx = u * 1024 + t;           // float4 index in slice
            const int i    = fidx >> 6;              // 64 float4 per row
            const int c4   = fidx & 63;
            *(float4*)&shRel[i * 264 + c4 * 4] =
                *(const float4*)(rbase + (size_t)i * 512 + c4 * 4);
        }
    }
    // adj slice [64 i][32 jl]: threads 0..511, one float4 each
    if (t < 512) {
        const int i2 = t >> 3, grp = t & 7;          // 8 float4 per row
        *(float4*)&shAdj[i2 * 36 + grp * 4] =
            *(const float4*)(adj2 + (size_t)b * 4096 + i2 * 64 + joff + grp * 4);
    }
    // K, V (swizzled), PE (r13 staging)
    {
        const int r  = t >> 4;               // 0..63
        const int gh = t & 15;
        const int g  = gh >> 1, lo = (gh & 1) * 4;
        const int d  = r * 64 + ((g ^ (r & 7)) << 3) + lo;
        const int so = r * 64 + g * 8 + lo;
        shK[d + 0] = Ks[(size_t)b * 4096 + so + 0];
        shK[d + 1] = Ks[(size_t)b * 4096 + so + 1];
        shK[d + 2] = Ks[(size_t)b * 4096 + so + 2];
        shK[d + 3] = Ks[(size_t)b * 4096 + so + 3];
        shV[d + 0] = Vs[(size_t)b * 4096 + so + 0];
        shV[d + 1] = Vs[(size_t)b * 4096 + so + 1];
        shV[d + 2] = Vs[(size_t)b * 4096 + so + 2];
        shV[d + 3] = Vs[(size_t)b * 4096 + so + 3];
        *(float4*)&shPE[t * 4] =
            *(const float4*)(PEs + ((size_t)b * 1024 + joff * 16) * 8 + t * 4);
    }
    float q[8];
    {
        const float* qp = Qs + (size_t)(b * 64 + j) * 64 + hh * 8;
        const float4 a = *(const float4*)qp;
        const float4 c = *(const float4*)(qp + 4);
        q[0]=a.x; q[1]=a.y; q[2]=a.z; q[3]=a.w;
        q[4]=c.x; q[5]=c.y; q[6]=c.z; q[7]=c.w;
    }
    __syncthreads();

    // ---- i-loop: PURE LDS. rel read = 64 consecutive floats/wave (free);
    // adj = 8-address broadcast; K/V = broadcast rows (2-way max).
    float den = 0.f;
    float wv[8] = {0.f,0.f,0.f,0.f,0.f,0.f,0.f,0.f};
    const int jh = t & 255;                       // j_local*8 + hh
    const float inv_scale = 0.35355339059327379f; // 1/sqrt(8)
    #pragma unroll 4
    for (int it = 0; it < 16; ++it) {
        const int i  = (q4 << 4) + it;            // wave-uniform
        const float rp = shRel[i * 264 + jh];
        const float a2 = shAdj[i * 36 + j_local];
        const int kb = i * 64 + ((hh ^ (i & 7)) << 3);
        const float4 kA = *(const float4*)&shK[kb];
        const float4 kB = *(const float4*)&shK[kb + 4];
        float s;
        s = kA.x * q[0];
        s = fmaf(kA.y, q[1], s); s = fmaf(kA.z, q[2], s); s = fmaf(kA.w, q[3], s);
        s = fmaf(kB.x, q[4], s); s = fmaf(kB.y, q[5], s); s = fmaf(kB.z, q[6], s);
        s = fmaf(kB.w, q[7], s);
        s = fmaf(s * inv_scale, a2, rp);          // raw score (pre proj_e, unclipped)
        const int kidx = (i - j - 1) & 63;
        if (kidx < 16) {                          // sparse edge (i -> j), unique owner
            const int x = (j_local * 16 + kidx) * 8 + hh;
            const float pe = shPE[x];             // read proj_e once
            shPE[x] = s;                          // overwrite with sc_sp (in-place)
            s += pe;                              // softmax sees sc_sp + proj_e
        }
        s = fminf(fmaxf(s, -5.f), 5.f);
        const float ex = __expf(s);
        den += ex;
        const float4 vA = *(const float4*)&shV[kb];
        const float4 vB = *(const float4*)&shV[kb + 4];
        wv[0] = fmaf(ex, vA.x, wv[0]); wv[1] = fmaf(ex, vA.y, wv[1]);
        wv[2] = fmaf(ex, vA.z, wv[2]); wv[3] = fmaf(ex, vA.w, wv[3]);
        wv[4] = fmaf(ex, vB.x, wv[4]); wv[5] = fmaf(ex, vB.y, wv[5]);
        wv[6] = fmaf(ex, vB.z, wv[6]); wv[7] = fmaf(ex, vB.w, wv[7]);
    }
    // ---- cross-wave quarter reduction: 4 deterministic barrier-ordered passes
    if (q4 == 0) {
        #pragma unroll
        for (int u = 0; u < 8; ++u) shRed[jh * 9 + u] = wv[u];
        shRed[jh * 9 + 8] = den;
    }
    __syncthreads();
    if (q4 == 1) {
        #pragma unroll
        for (int u = 0; u < 8; ++u) shRed[jh * 9 + u] += wv[u];
        shRed[jh * 9 + 8] += den;
    }
    __syncthreads();
    if (q4 == 2) {
        #pragma unroll
        for (int u = 0; u < 8; ++u) shRed[jh * 9 + u] += wv[u];
        shRed[jh * 9 + 8] += den;
    }
    __syncthreads();
    if (q4 == 3) {
        #pragma unroll
        for (int u = 0; u < 8; ++u) shRed[jh * 9 + u] += wv[u];
        shRed[jh * 9 + 8] += den;
    }
    __syncthreads();                 // loop + swaps + reduction complete

    // ---- P4: coalesced sc_sp dump (2 threads per sparse row); wV -> dead shK
    {
        const int row = t >> 1, pp = t & 1;
        *(float4*)(scsp + (size_t)((size_t)b * 1024 + joff * 16 + row) * 8 + pp * 4) =
            *(const float4*)&shPE[row * 8 + pp * 4];
    }
    if (t < 256) {                   // finalize (j,hh) = t
        const float* rd = &shRed[t * 9];
        const float id = 1.f / rd[8];
        float* wp = &shK[(t >> 3) * 64 + (t & 7) * 8];  // wV[32][64], plain layout
        *(float4*)(wp)     = make_float4(rd[0]*id, rd[1]*id, rd[2]*id, rd[3]*id);
        *(float4*)(wp + 4) = make_float4(rd[4]*id, rd[5]*id, rd[6]*id, rd[7]*id);
    }
    __syncthreads();

    // ---- P5: h_out = wV @ Wo^T + bo. thread = (rl = t>>5, c0 = (t&31)*2)
    {
        const int rl = t >> 5;
        const int c0 = (t & 31) * 2;
        float acc[2];
        acc[0] = bo[c0]; acc[1] = bo[c0 + 1];
        #pragma unroll 1
        for (int k0 = 0; k0 < 4; ++k0) {
            float tv[16];
            #pragma unroll
            for (int u = 0; u < 4; ++u) {
                const float4 x = *(const float4*)&shK[rl * 64 + k0 * 16 + u * 4];
                tv[u*4+0] = x.x; tv[u*4+1] = x.y; tv[u*4+2] = x.z; tv[u*4+3] = x.w;
            }
            #pragma unroll
            for (int u = 0; u < 2; ++u) {
                const float* wo = Wo + (c0 + u) * 64 + k0 * 16;
                #pragma unroll
                for (int k = 0; k < 16; ++k)
                    acc[u] = fmaf(tv[k], wo[k], acc[u]);
            }
        }
        float* orow = h_out + (size_t)(b * 64 + joff + rl) * 64 + c0;
        *(float2*)orow = make_float2(acc[0], acc[1]);
    }
}

// prep: M2/bc (fallback) + T[73][64] = [Woe^T ; M2^T ; bc].
__global__ void prep_kernel(const float* __restrict__ Wap, const float* __restrict__ bap,
                            const float* __restrict__ Woe, const float* __restrict__ boe,
                            float* __restrict__ M2, float* __restrict__ Tm, int hasT)
{
    const int tg = blockIdx.x * 64 + threadIdx.x;
    if (tg < 512) {
        const int c = tg >> 3, hq = tg & 7;
        float s = 0.f;
        #pragma unroll 8
        for (int k = 0; k < 64; ++k) s = fmaf(Woe[c * 64 + k], Wap[k * 8 + hq], s);
        M2[tg] = s;
    } else if (tg < 576) {
        const int c = tg - 512;
        float s = boe[c];
        #pragma unroll 8
        for (int k = 0; k < 64; ++k) s = fmaf(bap[k], Woe[c * 64 + k], s);
        M2[512 + c] = s;
    } else if (hasT && tg < 576 + 73 * 64) {
        const int idx = tg - 576;
        const int k = idx >> 6, c = idx & 63;
        float v;
        if (k < 64) {
            v = Woe[c * 64 + k];
        } else if (k < 72) {
            const int hq = k - 64;
            v = 0.f;
            #pragma unroll 8
            for (int kk = 0; kk < 64; ++kk)
                v = fmaf(Woe[c * 64 + kk], Wap[kk * 8 + hq], v);
        } else {
            v = boe[c];
            #pragma unroll 8
            for (int kk = 0; kk < 64; ++kk)
                v = fmaf(bap[kk], Woe[c * 64 + kk], v);
        }
        Tm[k * 64 + c] = v;
    }
}

// eoutT: ZERO-LDS flat k-outer (r17). 256 thr = 64 rows x 4 col-groups.
// ev[72] bulk in regs; weights via wave-uniform s_load per k (scalar pipe).
__global__ __launch_bounds__(256, 2) void eoutT_kernel(
    const float* __restrict__ e,
    const float* __restrict__ scsp,
    const float* __restrict__ Tm,      // [73][64]: Woe^T k=0..63, M2^T k=64..71, bc
    float* __restrict__ e_out)
{
    const int t   = threadIdx.x;
    const int r   = t & 63;
    const int w   = __builtin_amdgcn_readfirstlane(t >> 6);   // col group 0..3
    const int row = blockIdx.x * 64 + r;

    float ev[72];
    {
        const float* ep = e + (size_t)row * 64;
        #pragma unroll
        for (int v = 0; v < 16; ++v) {
            const float4 x = ((const float4*)ep)[v];
            ev[v*4+0] = x.x; ev[v*4+1] = x.y; ev[v*4+2] = x.z; ev[v*4+3] = x.w;
        }
        const float4 s0 = *(const float4*)(scsp + (size_t)row * 8);
        const float4 s1 = *(const float4*)(scsp + (size_t)row * 8 + 4);
        ev[64]=s0.x; ev[65]=s0.y; ev[66]=s0.z; ev[67]=s0.w;
        ev[68]=s1.x; ev[69]=s1.y; ev[70]=s1.z; ev[71]=s1.w;
    }
    const float* wbase = Tm + w * 16;              // wave-uniform
    float acc[16];
    #pragma unroll
    for (int u = 0; u < 16; ++u) acc[u] = wbase[72 * 64 + u];   // bc via s_load
    #pragma unroll
    for (int k = 0; k < 72; ++k) {
        const float* wk = wbase + k * 64;          // wave-uniform -> s_load_dwordx16
        #pragma unroll
        for (int u = 0; u < 16; ++u)
            acc[u] = fmaf(ev[k], wk[u], acc[u]);   // 16 independent FMAs
    }
    float* orow = e_out + (size_t)row * 64 + w * 16;
    #pragma unroll
    for (int u = 0; u < 4; ++u)
        *(float4*)&orow[u * 4] =
            make_float4(acc[u*4+0], acc[u*4+1], acc[u*4+2], acc[u*4+3]);
}

// Fallback eout if d_ws can't hold Tm (r10 shape).
__global__ __launch_bounds__(256, 2) void eout_kernel(
    const float* __restrict__ e,
    const float* __restrict__ scsp,
    const float* __restrict__ Woe,
    const float* __restrict__ M2g,
    float* __restrict__ e_out)
{
    __shared__ float shE[64 * 64];
    __shared__ float shS[64 * 8];
    const int t    = threadIdx.x;
    const int base = blockIdx.x * 64;
    {
        const int r = t >> 2, qq = t & 3;
        const float* ep = e + (size_t)(base + r) * 64 + qq * 16;
        #pragma unroll
        for (int u = 0; u < 4; ++u) {
            const float4 x = ((const float4*)ep)[u];
            const int cc = qq * 4 + u;
            *(float4*)&shE[r * 64 + ((cc ^ (r & 15)) << 2)] = x;
        }
    }
    if (t < 128) {
        const int r = t >> 1, pp = t & 1;
        *(float4*)&shS[r * 8 + pp * 4] =
            *(const float4*)(scsp + (size_t)(base + r) * 8 + pp * 4);
    }
    __syncthreads();
    const int w = __builtin_amdgcn_readfirstlane(t >> 6);
    const int r = t & 63;
    float sc[8];
    {
        const float4 a  = *(const float4*)&shS[r * 8];
        const float4 c4 = *(const float4*)&shS[r * 8 + 4];
        sc[0]=a.x; sc[1]=a.y; sc[2]=a.z; sc[3]=a.w;
        sc[4]=c4.x; sc[5]=c4.y; sc[6]=c4.z; sc[7]=c4.w;
    }
    float acc[16];
    #pragma unroll
    for (int u = 0; u < 16; ++u) {
        const int c = w * 16 + u;
        float s = M2g[512 + c];
        #pragma unroll
        for (int hq = 0; hq < 8; ++hq)
            s = fmaf(sc[hq], M2g[c * 8 + hq], s);
        acc[u] = s;
    }
    #pragma unroll
    for (int k0 = 0; k0 < 4; ++k0) {
        float ev[16];
        #pragma unroll
        for (int v = 0; v < 4; ++v) {
            const int cc = k0 * 4 + v;
            const float4 x = *(const float4*)&shE[r * 64 + ((cc ^ (r & 15)) << 2)];
            ev[v*4+0] = x.x; ev[v*4+1] = x.y; ev[v*4+2] = x.z; ev[v*4+3] = x.w;
        }
        #pragma unroll
        for (int u = 0; u < 16; ++u) {
            const float* wr = Woe + (w * 16 + u) * 64 + k0 * 16;
            #pragma unroll
            for (int k = 0; k < 16; ++k)
                acc[u] = fmaf(ev[k], wr[k], acc[u]);
        }
    }
    float* orow = e_out + (size_t)(base + r) * 64 + w * 16;
    #pragma unroll
    for (int u = 0; u < 4; ++u)
        *(float4*)&orow[u * 4] =
            make_float4(acc[u*4+0], acc[u*4+1], acc[u*4+2], acc[u*4+3]);
}

extern "C" void kernel_launch(void* const* d_in, const int* in_sizes, int n_in,
                              void* d_out, int out_size, void* d_ws, size_t ws_size,
                              hipStream_t stream) {
    const float* h    = (const float*)d_in[0];
    const float* e    = (const float*)d_in[1];
    const float* adj2 = (const float*)d_in[2];
    const float* rel  = (const float*)d_in[3];
    const float* Wq   = (const float*)d_in[4];  const float* bq  = (const float*)d_in[5];
    const float* Wk   = (const float*)d_in[6];  const float* bk  = (const float*)d_in[7];
    const float* Wv   = (const float*)d_in[8];  const float* bv  = (const float*)d_in[9];
    const float* Wpe  = (const float*)d_in[10]; const float* bpe = (const float*)d_in[11];
    const float* Wap  = (const float*)d_in[12]; const float* bap = (const float*)d_in[13];
    const float* Wo   = (const float*)d_in[14]; const float* bo  = (const float*)d_in[15];
    const float* Woe  = (const float*)d_in[16]; const float* boe = (const float*)d_in[17];

    float* out  = (float*)d_out;
    float* hout = out;                        // [16384*64]
    float* eout = out + 16384 * 64;           // [262144*64], staging (dead at eout time)
    float* Qs   = eout;
    float* Ks   = eout + 1048576;
    float* Vs   = eout + 2097152;
    float* PEs  = eout + 3145728;             // ends 5242880
    float* ws   = (float*)d_ws;
    float* scsp = ws;                         // [262144*8]
    float* M2g  = ws + 2097152;               // [576]
    float* Tm   = ws + 2098176;               // [73*64]
    const int hasT = (ws_size >= (size_t)(2098176 + 73 * 64) * sizeof(float)) ? 1 : 0;

    prep_kernel<<<dim3(82), dim3(64), 0, stream>>>(Wap, bap, Woe, boe, M2g, Tm, hasT);
    qkvpe_kernel<<<dim3(768), dim3(512), 0, stream>>>(
        h, e, Wq, bq, Wk, bk, Wv, bv, Wpe, bpe, Qs, Ks, Vs, PEs);
    attn_kernel<<<dim3(512), dim3(1024), 0, stream>>>(
        Qs, Ks, Vs, PEs, adj2, rel, Wo, bo, hout, scsp);
    if (hasT)
        eoutT_kernel<<<dim3(4096), dim3(256), 0, stream>>>(e, scsp, Tm, eout);
    else
        eout_kernel<<<dim3(4096), dim3(256), 0, stream>>>(e, scsp, Woe, M2g, eout);
}